// Round 20
// baseline (18353.950 us; speedup 1.0000x reference)
//
#include <hip/hip_runtime.h>
#include <cfloat>

#define B_ 32
#define N_ 4096
#define C_ 768
#define T_ 1000
#define K_ 20

#define PHC 32            // floats per c-phase (one MFMA K=32 step)
#define NPH (C_/PHC)      // 24 phases
#define SPP 4             // phases per super-phase (512B row bursts)
#define NSP (NPH/SPP)     // 6 super-phases
#define GAP_TH 1e-4f
#define FMAX_B 512        // flag slots per batch

typedef float f32x4 __attribute__((ext_vector_type(4)));
typedef int   i32x4 __attribute__((ext_vector_type(4)));
typedef short s16x8 __attribute__((ext_vector_type(8)));   // 8 bf16 (4 VGPR)

__device__ __forceinline__ unsigned short bf_rne(float x) {
    unsigned u = __float_as_uint(x);
    return (unsigned short)((u + 0x7fffu + ((u >> 16) & 1u)) >> 16);
}
__device__ __forceinline__ int aload(const int* p) {
    return __hip_atomic_load(p, __ATOMIC_RELAXED, __HIP_MEMORY_SCOPE_AGENT);
}
__device__ __forceinline__ void astore(int* p, int v) {
    __hip_atomic_store(p, v, __ATOMIC_RELAXED, __HIP_MEMORY_SCOPE_AGENT);
}

// ---------------- K1a: vg_logit in fp64 (+ zero control block) ----------------
__global__ __launch_bounds__(256) void k1_logits(const float* __restrict__ g_feat,
                                                 const float* __restrict__ text,
                                                 double* __restrict__ logits,
                                                 int* __restrict__ ctrl) {
    int b = blockIdx.x;
    int wid = threadIdx.x >> 6, lane = threadIdx.x & 63;
    int t = blockIdx.y * 4 + wid;           // grid.y = 250 -> t in [0,1000)
    if (b == 0 && blockIdx.y == 0) {
        // ctrl: cnt[640] | flagc[32] | done[32] | ready[32] | scale[640] = 1376 ints
        for (int i = threadIdx.x; i < 1376; i += 256) ctrl[i] = 0;
    }
    const float* g = g_feat + b * C_;
    const float* e = text + t * C_;
    double s = 0.0;
    #pragma unroll
    for (int j = 0; j < 12; ++j) {
        int c = lane + 64 * j;
        s += (double)g[c] * (double)e[c];
    }
    #pragma unroll
    for (int m = 32; m; m >>= 1) s += __shfl_xor(s, m);
    if (lane == 0) logits[b * T_ + t] = s;
}

// ---------------- K1b: top-20 + gather + A-fragment-ordered bf16 hi/lo pack ----------------
__global__ __launch_bounds__(256) void k1b_topk(const double* __restrict__ logits,
                                                const float* __restrict__ text,
                                                float* __restrict__ agg,
                                                unsigned short* __restrict__ Epk) {
    __shared__ unsigned short hiL[32 * C_];   // 48 KB
    __shared__ unsigned short loL[32 * C_];   // 48 KB
    __shared__ int ssel[K_];
    int b = blockIdx.x, tid = threadIdx.x, lane = tid & 63;
    if (tid < 64) {
        double v[16];
        #pragma unroll
        for (int j = 0; j < 16; ++j) {
            int t = lane + 64 * j;
            v[j] = (t < T_) ? logits[b * T_ + t] : -DBL_MAX;
        }
        for (int it = 0; it < K_; ++it) {
            double bv = -DBL_MAX; int bi = 0x7fffffff;
            #pragma unroll
            for (int j = 0; j < 16; ++j) {
                int t = lane + 64 * j;
                if (v[j] > bv) { bv = v[j]; bi = t; }
            }
            #pragma unroll
            for (int m = 32; m; m >>= 1) {
                double ov = __shfl_xor(bv, m); int oi = __shfl_xor(bi, m);
                if (ov > bv || (ov == bv && oi < bi)) { bv = ov; bi = oi; }
            }
            if (lane == 0) ssel[it] = bi;
            #pragma unroll
            for (int j = 0; j < 16; ++j) {
                int t = lane + 64 * j;
                if (t == bi) v[j] = -DBL_MAX;
            }
        }
    }
    __syncthreads();
    for (int i = tid; i < 32 * C_; i += 256) {
        int r = i / C_, c = i - r * C_;
        float v = (r < K_) ? text[ssel[r] * C_ + c] : 0.f;
        if (r < K_) agg[b * K_ * C_ + i] = v;
        unsigned u = __float_as_uint(v);
        float fh = __uint_as_float(u & 0xffff0000u);
        hiL[i] = (unsigned short)(u >> 16);
        loL[i] = bf_rne(v - fh);
    }
    __syncthreads();
    for (int i = tid; i < 24 * 256; i += 256) {
        int p = i >> 8, r = i & 255, f = r >> 6, ln = r & 63;
        int row = (f & 1) * 16 + (ln & 15);
        int col = p * 32 + (ln >> 4) * 8;
        const unsigned short* src = ((f < 2) ? hiL : loL) + row * C_ + col;
        *(s16x8*)(Epk + ((size_t)b * 6144 + i) * 8) = *(const s16x8*)src;
    }
}

// ---------------- KF: fused pipelined argmax-read + refine + out-write ----------------
// R20 = R19 with the done-counter protocol FIXED: arrival counted once per WAVE
// (lane 0 fetch_add, shfl-broadcast), refiner entered by the whole 256th wave.
// (R19 counted per-lane: refiner fired on ONE LANE of the 4th wave -> 19/20
// scales stayed 0 -> zero output, absmax == max|ref|.)
__global__ __launch_bounds__(256, 4) void kf_pipe(const float* __restrict__ feat,
                                                  const unsigned short* __restrict__ Epk,
                                                  const float* __restrict__ agg,
                                                  int* __restrict__ kidx,
                                                  int* __restrict__ ctrl,
                                                  int* __restrict__ flagl,
                                                  float* __restrict__ out) {
    int* cnt   = ctrl;             // [640]
    int* flagc = ctrl + 640;       // [32]
    int* done  = ctrl + 672;       // [32]
    int* ready = ctrl + 704;       // [32]
    int* scale = ctrl + 736;       // [640] float bits

    int tid = threadIdx.x, wid = tid >> 6, lane = tid & 63;
    int j = blockIdx.x, jb = j >> 8, t16 = j & 255;
    int n0 = t16 * 16;
    int prow = lane & 15, g = lane >> 4;

    #pragma unroll 1
    for (int s = 0; s < 10; ++s) {
        if (wid == 0 && s < 8) {
            // ---------- reader: argmax tile t16 of batch b ----------
            int b = 4 * s + jb;
            const float* fp0 = feat + ((size_t)b * N_ + n0 + prow) * C_ + g * 8;
            const unsigned short* Eb = Epk + (size_t)b * 6144 * 8;

            f32x4 fA[2 * SPP], fB[2 * SPP];
            s16x8 Ah0, Ah1, Al0, Al1;
            f32x4 acc0 = (f32x4)0.f, acc1 = (f32x4)0.f;

            auto LOADSP = [&](int sp, f32x4* fr) {
                #pragma unroll
                for (int q = 0; q < SPP; ++q) {
                    fr[2*q]   = __builtin_nontemporal_load((const f32x4*)(fp0 + (sp*SPP+q)*PHC));
                    fr[2*q+1] = __builtin_nontemporal_load((const f32x4*)(fp0 + (sp*SPP+q)*PHC + 4));
                }
            };
            auto LOADA = [&](int p) {
                const s16x8* ap = (const s16x8*)(Eb + (size_t)p * 256 * 8);
                Ah0 = ap[lane]; Ah1 = ap[64 + lane];
                Al0 = ap[128 + lane]; Al1 = ap[192 + lane];
            };
            auto CVT = [&](f32x4 a, f32x4 c, s16x8& H, s16x8& L) {
                float x[8] = { a.x, a.y, a.z, a.w, c.x, c.y, c.z, c.w };
                unsigned hu[8], lu[8];
                #pragma unroll
                for (int q = 0; q < 8; ++q) {
                    unsigned u = __float_as_uint(x[q]);
                    hu[q] = u >> 16;
                    lu[q] = bf_rne(x[q] - __uint_as_float(u & 0xffff0000u));
                }
                i32x4 hv = { (int)(hu[0]|(hu[1]<<16)), (int)(hu[2]|(hu[3]<<16)),
                             (int)(hu[4]|(hu[5]<<16)), (int)(hu[6]|(hu[7]<<16)) };
                i32x4 lv = { (int)(lu[0]|(lu[1]<<16)), (int)(lu[2]|(lu[3]<<16)),
                             (int)(lu[4]|(lu[5]<<16)), (int)(lu[6]|(lu[7]<<16)) };
                H = __builtin_bit_cast(s16x8, hv);
                L = __builtin_bit_cast(s16x8, lv);
            };

            LOADSP(0, fA);
            #pragma unroll 1
            for (int sp = 0; sp < NSP; ++sp) {
                f32x4* cur = (sp & 1) ? fB : fA;
                f32x4* nxt = (sp & 1) ? fA : fB;
                if (sp + 1 < NSP) LOADSP(sp + 1, nxt);
                #pragma unroll
                for (int q = 0; q < SPP; ++q) {
                    LOADA(sp * SPP + q);
                    s16x8 Bh, Bl;
                    CVT(cur[2*q], cur[2*q+1], Bh, Bl);
                    acc0 = __builtin_amdgcn_mfma_f32_16x16x32_bf16(Ah0, Bh, acc0, 0, 0, 0);
                    acc1 = __builtin_amdgcn_mfma_f32_16x16x32_bf16(Ah1, Bh, acc1, 0, 0, 0);
                    acc0 = __builtin_amdgcn_mfma_f32_16x16x32_bf16(Ah0, Bl, acc0, 0, 0, 0);
                    acc1 = __builtin_amdgcn_mfma_f32_16x16x32_bf16(Ah1, Bl, acc1, 0, 0, 0);
                    acc0 = __builtin_amdgcn_mfma_f32_16x16x32_bf16(Al0, Bh, acc0, 0, 0, 0);
                    acc1 = __builtin_amdgcn_mfma_f32_16x16x32_bf16(Al1, Bh, acc1, 0, 0, 0);
                }
            }

            // top-2 over k (C/D: col=lane&15=px, row-class=(lane>>4)*4+reg)
            int kb = g * 4;
            float m1 = acc0[0]; int i1 = kb; float m2 = -FLT_MAX;
            #pragma unroll
            for (int r = 1; r < 4; ++r) {
                float v = acc0[r];
                if (v > m1) { m2 = m1; m1 = v; i1 = kb + r; }
                else if (v > m2) m2 = v;
            }
            if (g == 0) {
                #pragma unroll
                for (int r = 0; r < 4; ++r) {
                    float v = acc1[r];
                    if (v > m1) { m2 = m1; m1 = v; i1 = 16 + r; }
                    else if (v > m2) m2 = v;
                }
            }
            #pragma unroll
            for (int m = 16; m < 64; m <<= 1) {
                float om1 = __shfl_xor(m1, m); int oi1 = __shfl_xor(i1, m);
                float om2 = __shfl_xor(m2, m);
                if (om1 > m1 || (om1 == m1 && oi1 < i1)) { m2 = fmaxf(m1, om2); m1 = om1; i1 = oi1; }
                else { m2 = fmaxf(m2, om1); }
            }
            if (lane < 16) {
                astore(&kidx[b * N_ + n0 + lane], i1);
                if (m1 - m2 < GAP_TH) {
                    int pos = atomicAdd(&flagc[b], 1);
                    if (pos < FMAX_B) astore(&flagl[b * FMAX_B + pos], b * N_ + n0 + lane);
                }
            }
            int myc = 0;
            #pragma unroll 1
            for (int k = 0; k < K_; ++k) {
                unsigned long long mm = __ballot(lane < 16 && i1 == k);
                if (lane == k) myc = __popcll(mm);
            }
            if (lane < K_ && myc) atomicAdd(&cnt[b * K_ + lane], myc);

            // wave-level arrival: ONE increment per wave, whole wave refines
            int ret = 0;
            if (lane == 0)
                ret = __hip_atomic_fetch_add(&done[b], 1, __ATOMIC_ACQ_REL, __HIP_MEMORY_SCOPE_AGENT);
            ret = __shfl(ret, 0);
            if (ret == 255) {
                // ---------- refiner (full wave): fp64 re-decision + scales ----------
                int c = 0;
                if (lane < K_) c = aload(&cnt[b * K_ + lane]);
                int nf = aload(&flagc[b]);
                if (nf > FMAX_B) nf = FMAX_B;
                if (nf < 0) nf = 0;
                const float* ebase = agg + (size_t)b * K_ * C_;
                #pragma unroll 1
                for (int e = 0; e < nf; ++e) {
                    int pix = aload(&flagl[b * FMAX_B + e]);
                    if (pix < 0) pix = 0;
                    if (pix > B_ * N_ - 1) pix = B_ * N_ - 1;
                    const float* fr = feat + (size_t)pix * C_;
                    double fd[12];
                    #pragma unroll
                    for (int q = 0; q < 12; ++q) fd[q] = (double)fr[lane + 64 * q];
                    double best = -DBL_MAX; int bi = 0;
                    #pragma unroll 1
                    for (int k = 0; k < K_; ++k) {
                        const float* er = ebase + k * C_;
                        double sd = 0.0;
                        #pragma unroll
                        for (int q = 0; q < 12; ++q) sd += fd[q] * (double)er[lane + 64 * q];
                        #pragma unroll
                        for (int m = 32; m; m >>= 1) sd += __shfl_xor(sd, m);
                        if (sd > best) { best = sd; bi = k; }
                    }
                    int old = aload(&kidx[pix]);
                    if (old < 0) old = 0;
                    if (old > K_ - 1) old = K_ - 1;
                    if (old != bi) {
                        if (lane == 0) astore(&kidx[pix], bi);
                        if (lane == old) c -= 1;
                        if (lane == bi)  c += 1;
                    }
                }
                if (lane < K_) astore(&scale[b * K_ + lane],
                                      __float_as_int(1.0f / ((float)c + 1.0f)));
                __hip_atomic_store(&ready[b], 1, __ATOMIC_RELEASE, __HIP_MEMORY_SCOPE_AGENT);
            }
        }

        if (wid > 0 && s >= 2) {
            // ---------- writers: 16 rows of batch bw (2-step delay) ----------
            int bw = 4 * (s - 2) + jb;
            while (__hip_atomic_load(&ready[bw], __ATOMIC_ACQUIRE, __HIP_MEMORY_SCOPE_AGENT) == 0)
                __builtin_amdgcn_s_sleep(8);
            const f32x4* agg4 = (const f32x4*)(agg + (size_t)bw * K_ * C_);
            f32x4* out4 = (f32x4*)out;
            int rb = (wid == 1) ? 0 : (wid == 2) ? 6 : 11;
            int re = (wid == 1) ? 6 : (wid == 2) ? 11 : 16;
            #pragma unroll 1
            for (int r = rb; r < re; ++r) {
                int n = bw * N_ + n0 + r;
                int kk = aload(&kidx[n]);
                if (kk < 0) kk = 0;
                if (kk > K_ - 1) kk = K_ - 1;
                float sc = __int_as_float(aload(&scale[bw * K_ + kk]));
                const f32x4* a4 = agg4 + (size_t)kk * (C_ / 4);
                f32x4* o4 = out4 + (size_t)n * (C_ / 4);
                __builtin_nontemporal_store(a4[lane] * sc,       &o4[lane]);
                __builtin_nontemporal_store(a4[lane + 64] * sc,  &o4[lane + 64]);
                __builtin_nontemporal_store(a4[lane + 128] * sc, &o4[lane + 128]);
            }
        }
    }
}

extern "C" void kernel_launch(void* const* d_in, const int* in_sizes, int n_in,
                              void* d_out, int out_size, void* d_ws, size_t ws_size,
                              hipStream_t stream) {
    const float* g_feat = (const float*)d_in[0];
    const float* feat   = (const float*)d_in[1];
    // d_in[2] = tau: positive scale, numerically irrelevant (attn == y_hard exactly)
    const float* text   = (const float*)d_in[3];
    float* out = (float*)d_out;

    char* ws = (char*)d_ws;
    double* logits        = (double*)(ws + 0);         // 256000 B
    float*  agg           = (float*) (ws + 262144);    // 1966080 B -> ends 2228224
    int*    ctrl          = (int*)   (ws + 2228224);   // 5504 B (cnt|flagc|done|ready|scale)
    int*    flagl         = (int*)   (ws + 2233728);   // 65536 B
    int*    kidx          = (int*)   (ws + 2299264);   // 524288 B
    unsigned short* Epk   = (unsigned short*)(ws + 2823552);  // 3145728 B

    k1_logits<<<dim3(32, 250), 256, 0, stream>>>(g_feat, text, logits, ctrl);
    k1b_topk<<<32, 256, 0, stream>>>(logits, text, agg, Epk);
    kf_pipe<<<1024, 256, 0, stream>>>(feat, Epk, agg, kidx, ctrl, flagl, out);
}

// Round 21
// 895.810 us; speedup vs baseline: 20.4887x; 20.4887x over previous
//
#include <hip/hip_runtime.h>
#include <cfloat>

#define B_ 32
#define N_ 4096
#define C_ 768
#define T_ 1000
#define K_ 20

#define PHC 32            // floats per c-phase (one MFMA K=32 step)
#define NPH (C_/PHC)      // 24 phases
#define SPP 4             // phases per super-phase (512B row bursts)
#define NSP (NPH/SPP)     // 6 super-phases
#define GAP_TH 1e-4f
#define FMAX_B 512        // flag slots per batch

typedef float f32x4 __attribute__((ext_vector_type(4)));
typedef int   i32x4 __attribute__((ext_vector_type(4)));
typedef short s16x8 __attribute__((ext_vector_type(8)));   // 8 bf16 (4 VGPR)

__device__ __forceinline__ unsigned short bf_rne(float x) {
    unsigned u = __float_as_uint(x);
    return (unsigned short)((u + 0x7fffu + ((u >> 16) & 1u)) >> 16);
}
__device__ __forceinline__ int aload(const int* p) {
    return __hip_atomic_load(p, __ATOMIC_RELAXED, __HIP_MEMORY_SCOPE_AGENT);
}
__device__ __forceinline__ void astore(int* p, int v) {
    __hip_atomic_store(p, v, __ATOMIC_RELAXED, __HIP_MEMORY_SCOPE_AGENT);
}

// ctrl layout (ints): cnt[640] | flagc[32] | done[32*16] | ready[32*16] | scale[640]
#define CT_CNT   0
#define CT_FLAGC 640
#define CT_DONE  672
#define CT_READY 1184
#define CT_SCALE 1696
#define CT_TOTAL 2336

// ---------------- K1a: vg_logit in fp64 (+ zero control block) ----------------
__global__ __launch_bounds__(256) void k1_logits(const float* __restrict__ g_feat,
                                                 const float* __restrict__ text,
                                                 double* __restrict__ logits,
                                                 int* __restrict__ ctrl) {
    int b = blockIdx.x;
    int wid = threadIdx.x >> 6, lane = threadIdx.x & 63;
    int t = blockIdx.y * 4 + wid;           // grid.y = 250 -> t in [0,1000)
    if (b == 0 && blockIdx.y == 0) {
        for (int i = threadIdx.x; i < CT_TOTAL; i += 256) ctrl[i] = 0;
    }
    const float* g = g_feat + b * C_;
    const float* e = text + t * C_;
    double s = 0.0;
    #pragma unroll
    for (int j = 0; j < 12; ++j) {
        int c = lane + 64 * j;
        s += (double)g[c] * (double)e[c];
    }
    #pragma unroll
    for (int m = 32; m; m >>= 1) s += __shfl_xor(s, m);
    if (lane == 0) logits[b * T_ + t] = s;
}

// ---------------- K1b: top-20 + gather + A-fragment-ordered bf16 hi/lo pack ----------------
__global__ __launch_bounds__(256) void k1b_topk(const double* __restrict__ logits,
                                                const float* __restrict__ text,
                                                float* __restrict__ agg,
                                                unsigned short* __restrict__ Epk) {
    __shared__ unsigned short hiL[32 * C_];   // 48 KB
    __shared__ unsigned short loL[32 * C_];   // 48 KB
    __shared__ int ssel[K_];
    int b = blockIdx.x, tid = threadIdx.x, lane = tid & 63;
    if (tid < 64) {
        double v[16];
        #pragma unroll
        for (int j = 0; j < 16; ++j) {
            int t = lane + 64 * j;
            v[j] = (t < T_) ? logits[b * T_ + t] : -DBL_MAX;
        }
        for (int it = 0; it < K_; ++it) {
            double bv = -DBL_MAX; int bi = 0x7fffffff;
            #pragma unroll
            for (int j = 0; j < 16; ++j) {
                int t = lane + 64 * j;
                if (v[j] > bv) { bv = v[j]; bi = t; }
            }
            #pragma unroll
            for (int m = 32; m; m >>= 1) {
                double ov = __shfl_xor(bv, m); int oi = __shfl_xor(bi, m);
                if (ov > bv || (ov == bv && oi < bi)) { bv = ov; bi = oi; }
            }
            if (lane == 0) ssel[it] = bi;
            #pragma unroll
            for (int j = 0; j < 16; ++j) {
                int t = lane + 64 * j;
                if (t == bi) v[j] = -DBL_MAX;
            }
        }
    }
    __syncthreads();
    for (int i = tid; i < 32 * C_; i += 256) {
        int r = i / C_, c = i - r * C_;
        float v = (r < K_) ? text[ssel[r] * C_ + c] : 0.f;
        if (r < K_) agg[b * K_ * C_ + i] = v;
        unsigned u = __float_as_uint(v);
        float fh = __uint_as_float(u & 0xffff0000u);
        hiL[i] = (unsigned short)(u >> 16);
        loL[i] = bf_rne(v - fh);
    }
    __syncthreads();
    for (int i = tid; i < 24 * 256; i += 256) {
        int p = i >> 8, r = i & 255, f = r >> 6, ln = r & 63;
        int row = (f & 1) * 16 + (ln & 15);
        int col = p * 32 + (ln >> 4) * 8;
        const unsigned short* src = ((f < 2) ? hiL : loL) + row * C_ + col;
        *(s16x8*)(Epk + ((size_t)b * 6144 + i) * 8) = *(const s16x8*)src;
    }
}

// ---------------- KF: fused pipelined argmax-read + refine + out-write ----------------
// R21 = R20 with the spin protocol detoxified: writers poll ready[] with
// RELAXED loads (no per-iteration cache invalidate) + s_sleep back-off, and
// issue ONE acquire fence after observing the flag. R20's per-iteration
// agent-ACQUIRE polls caused a chip-wide L1/L2 invalidation storm (34 GB/s
// HBM, VALU 0.2%, 18.5 ms). done[]/ready[] padded to 64B stride.
__global__ __launch_bounds__(256, 4) void kf_pipe(const float* __restrict__ feat,
                                                  const unsigned short* __restrict__ Epk,
                                                  const float* __restrict__ agg,
                                                  int* __restrict__ kidx,
                                                  int* __restrict__ ctrl,
                                                  int* __restrict__ flagl,
                                                  float* __restrict__ out) {
    int* cnt   = ctrl + CT_CNT;     // [640]
    int* flagc = ctrl + CT_FLAGC;   // [32]
    int* done  = ctrl + CT_DONE;    // [32*16] stride 16
    int* ready = ctrl + CT_READY;   // [32*16] stride 16
    int* scale = ctrl + CT_SCALE;   // [640] float bits

    int tid = threadIdx.x, wid = tid >> 6, lane = tid & 63;
    int j = blockIdx.x, jb = j >> 8, t16 = j & 255;
    int n0 = t16 * 16;
    int prow = lane & 15, g = lane >> 4;

    #pragma unroll 1
    for (int s = 0; s < 10; ++s) {
        if (wid == 0 && s < 8) {
            // ---------- reader: argmax tile t16 of batch b ----------
            int b = 4 * s + jb;
            const float* fp0 = feat + ((size_t)b * N_ + n0 + prow) * C_ + g * 8;
            const unsigned short* Eb = Epk + (size_t)b * 6144 * 8;

            f32x4 fA[2 * SPP], fB[2 * SPP];
            s16x8 Ah0, Ah1, Al0, Al1;
            f32x4 acc0 = (f32x4)0.f, acc1 = (f32x4)0.f;

            auto LOADSP = [&](int sp, f32x4* fr) {
                #pragma unroll
                for (int q = 0; q < SPP; ++q) {
                    fr[2*q]   = __builtin_nontemporal_load((const f32x4*)(fp0 + (sp*SPP+q)*PHC));
                    fr[2*q+1] = __builtin_nontemporal_load((const f32x4*)(fp0 + (sp*SPP+q)*PHC + 4));
                }
            };
            auto LOADA = [&](int p) {
                const s16x8* ap = (const s16x8*)(Eb + (size_t)p * 256 * 8);
                Ah0 = ap[lane]; Ah1 = ap[64 + lane];
                Al0 = ap[128 + lane]; Al1 = ap[192 + lane];
            };
            auto CVT = [&](f32x4 a, f32x4 c, s16x8& H, s16x8& L) {
                float x[8] = { a.x, a.y, a.z, a.w, c.x, c.y, c.z, c.w };
                unsigned hu[8], lu[8];
                #pragma unroll
                for (int q = 0; q < 8; ++q) {
                    unsigned u = __float_as_uint(x[q]);
                    hu[q] = u >> 16;
                    lu[q] = bf_rne(x[q] - __uint_as_float(u & 0xffff0000u));
                }
                i32x4 hv = { (int)(hu[0]|(hu[1]<<16)), (int)(hu[2]|(hu[3]<<16)),
                             (int)(hu[4]|(hu[5]<<16)), (int)(hu[6]|(hu[7]<<16)) };
                i32x4 lv = { (int)(lu[0]|(lu[1]<<16)), (int)(lu[2]|(lu[3]<<16)),
                             (int)(lu[4]|(lu[5]<<16)), (int)(lu[6]|(lu[7]<<16)) };
                H = __builtin_bit_cast(s16x8, hv);
                L = __builtin_bit_cast(s16x8, lv);
            };

            LOADSP(0, fA);
            #pragma unroll 1
            for (int sp = 0; sp < NSP; ++sp) {
                f32x4* cur = (sp & 1) ? fB : fA;
                f32x4* nxt = (sp & 1) ? fA : fB;
                if (sp + 1 < NSP) LOADSP(sp + 1, nxt);
                #pragma unroll
                for (int q = 0; q < SPP; ++q) {
                    LOADA(sp * SPP + q);
                    s16x8 Bh, Bl;
                    CVT(cur[2*q], cur[2*q+1], Bh, Bl);
                    acc0 = __builtin_amdgcn_mfma_f32_16x16x32_bf16(Ah0, Bh, acc0, 0, 0, 0);
                    acc1 = __builtin_amdgcn_mfma_f32_16x16x32_bf16(Ah1, Bh, acc1, 0, 0, 0);
                    acc0 = __builtin_amdgcn_mfma_f32_16x16x32_bf16(Ah0, Bl, acc0, 0, 0, 0);
                    acc1 = __builtin_amdgcn_mfma_f32_16x16x32_bf16(Ah1, Bl, acc1, 0, 0, 0);
                    acc0 = __builtin_amdgcn_mfma_f32_16x16x32_bf16(Al0, Bh, acc0, 0, 0, 0);
                    acc1 = __builtin_amdgcn_mfma_f32_16x16x32_bf16(Al1, Bh, acc1, 0, 0, 0);
                }
            }

            // top-2 over k (C/D: col=lane&15=px, row-class=(lane>>4)*4+reg)
            int kb = g * 4;
            float m1 = acc0[0]; int i1 = kb; float m2 = -FLT_MAX;
            #pragma unroll
            for (int r = 1; r < 4; ++r) {
                float v = acc0[r];
                if (v > m1) { m2 = m1; m1 = v; i1 = kb + r; }
                else if (v > m2) m2 = v;
            }
            if (g == 0) {
                #pragma unroll
                for (int r = 0; r < 4; ++r) {
                    float v = acc1[r];
                    if (v > m1) { m2 = m1; m1 = v; i1 = 16 + r; }
                    else if (v > m2) m2 = v;
                }
            }
            #pragma unroll
            for (int m = 16; m < 64; m <<= 1) {
                float om1 = __shfl_xor(m1, m); int oi1 = __shfl_xor(i1, m);
                float om2 = __shfl_xor(m2, m);
                if (om1 > m1 || (om1 == m1 && oi1 < i1)) { m2 = fmaxf(m1, om2); m1 = om1; i1 = oi1; }
                else { m2 = fmaxf(m2, om1); }
            }
            if (lane < 16) {
                astore(&kidx[b * N_ + n0 + lane], i1);
                if (m1 - m2 < GAP_TH) {
                    int pos = atomicAdd(&flagc[b], 1);
                    if (pos < FMAX_B) astore(&flagl[b * FMAX_B + pos], b * N_ + n0 + lane);
                }
            }
            int myc = 0;
            #pragma unroll 1
            for (int k = 0; k < K_; ++k) {
                unsigned long long mm = __ballot(lane < 16 && i1 == k);
                if (lane == k) myc = __popcll(mm);
            }
            if (lane < K_ && myc) atomicAdd(&cnt[b * K_ + lane], myc);

            // wave-level arrival: ONE increment per wave, whole wave refines
            int ret = 0;
            if (lane == 0)
                ret = __hip_atomic_fetch_add(&done[b * 16], 1, __ATOMIC_ACQ_REL, __HIP_MEMORY_SCOPE_AGENT);
            ret = __shfl(ret, 0);
            if (ret == 255) {
                // ---------- refiner (full wave): fp64 re-decision + scales ----------
                int c = 0;
                if (lane < K_) c = aload(&cnt[b * K_ + lane]);
                int nf = aload(&flagc[b]);
                if (nf > FMAX_B) nf = FMAX_B;
                if (nf < 0) nf = 0;
                const float* ebase = agg + (size_t)b * K_ * C_;
                #pragma unroll 1
                for (int e = 0; e < nf; ++e) {
                    int pix = aload(&flagl[b * FMAX_B + e]);
                    if (pix < 0) pix = 0;
                    if (pix > B_ * N_ - 1) pix = B_ * N_ - 1;
                    const float* fr = feat + (size_t)pix * C_;
                    double fd[12];
                    #pragma unroll
                    for (int q = 0; q < 12; ++q) fd[q] = (double)fr[lane + 64 * q];
                    double best = -DBL_MAX; int bi = 0;
                    #pragma unroll 1
                    for (int k = 0; k < K_; ++k) {
                        const float* er = ebase + k * C_;
                        double sd = 0.0;
                        #pragma unroll
                        for (int q = 0; q < 12; ++q) sd += fd[q] * (double)er[lane + 64 * q];
                        #pragma unroll
                        for (int m = 32; m; m >>= 1) sd += __shfl_xor(sd, m);
                        if (sd > best) { best = sd; bi = k; }
                    }
                    int old = aload(&kidx[pix]);
                    if (old < 0) old = 0;
                    if (old > K_ - 1) old = K_ - 1;
                    if (old != bi) {
                        if (lane == 0) astore(&kidx[pix], bi);
                        if (lane == old) c -= 1;
                        if (lane == bi)  c += 1;
                    }
                }
                if (lane < K_) astore(&scale[b * K_ + lane],
                                      __float_as_int(1.0f / ((float)c + 1.0f)));
                __hip_atomic_store(&ready[b * 16], 1, __ATOMIC_RELEASE, __HIP_MEMORY_SCOPE_AGENT);
            }
        }

        if (wid > 0 && s >= 2) {
            // ---------- writers: 16 rows of batch bw (2-step delay) ----------
            int bw = 4 * (s - 2) + jb;
            // RELAXED poll (no cache maintenance) + back-off; one acquire fence after.
            while (__hip_atomic_load(&ready[bw * 16], __ATOMIC_RELAXED, __HIP_MEMORY_SCOPE_AGENT) == 0)
                __builtin_amdgcn_s_sleep(32);
            __builtin_amdgcn_fence(__ATOMIC_ACQUIRE, "agent");
            const f32x4* agg4 = (const f32x4*)(agg + (size_t)bw * K_ * C_);
            f32x4* out4 = (f32x4*)out;
            int rb = (wid == 1) ? 0 : (wid == 2) ? 6 : 11;
            int re = (wid == 1) ? 6 : (wid == 2) ? 11 : 16;
            #pragma unroll 1
            for (int r = rb; r < re; ++r) {
                int n = bw * N_ + n0 + r;
                int kk = aload(&kidx[n]);
                if (kk < 0) kk = 0;
                if (kk > K_ - 1) kk = K_ - 1;
                float sc = __int_as_float(aload(&scale[bw * K_ + kk]));
                const f32x4* a4 = agg4 + (size_t)kk * (C_ / 4);
                f32x4* o4 = out4 + (size_t)n * (C_ / 4);
                __builtin_nontemporal_store(a4[lane] * sc,       &o4[lane]);
                __builtin_nontemporal_store(a4[lane + 64] * sc,  &o4[lane + 64]);
                __builtin_nontemporal_store(a4[lane + 128] * sc, &o4[lane + 128]);
            }
        }
    }
}

extern "C" void kernel_launch(void* const* d_in, const int* in_sizes, int n_in,
                              void* d_out, int out_size, void* d_ws, size_t ws_size,
                              hipStream_t stream) {
    const float* g_feat = (const float*)d_in[0];
    const float* feat   = (const float*)d_in[1];
    // d_in[2] = tau: positive scale, numerically irrelevant (attn == y_hard exactly)
    const float* text   = (const float*)d_in[3];
    float* out = (float*)d_out;

    char* ws = (char*)d_ws;
    double* logits        = (double*)(ws + 0);         // 256000 B
    float*  agg           = (float*) (ws + 262144);    // 1966080 B -> ends 2228224
    int*    ctrl          = (int*)   (ws + 2228224);   // 9344 B (cnt|flagc|done|ready|scale)
    int*    flagl         = (int*)   (ws + 2237568);   // 65536 B
    int*    kidx          = (int*)   (ws + 2303104);   // 524288 B
    unsigned short* Epk   = (unsigned short*)(ws + 2827392);  // 3145728 B

    k1_logits<<<dim3(32, 250), 256, 0, stream>>>(g_feat, text, logits, ctrl);
    k1b_topk<<<32, 256, 0, stream>>>(logits, text, agg, Epk);
    kf_pipe<<<1024, 256, 0, stream>>>(feat, Epk, agg, kidx, ctrl, flagl, out);
}

// Round 22
// 265.235 us; speedup vs baseline: 69.1987x; 3.3774x over previous
//
#include <hip/hip_runtime.h>
#include <cfloat>

#define B_ 32
#define N_ 4096
#define C_ 768
#define T_ 1000
#define K_ 20

#define PHC 32            // floats per c-phase (one MFMA K=32 step)
#define NPH (C_/PHC)      // 24 phases
#define SPP 4             // phases per super-phase (512B row bursts)
#define NSP (NPH/SPP)     // 6 super-phases
#define GAP_TH 1e-4f
#define MAXF 16384

typedef float f32x4 __attribute__((ext_vector_type(4)));
typedef int   i32x4 __attribute__((ext_vector_type(4)));
typedef short s16x8 __attribute__((ext_vector_type(8)));   // 8 bf16 (4 VGPR)

__device__ __forceinline__ unsigned short bf_rne(float x) {
    unsigned u = __float_as_uint(x);
    return (unsigned short)((u + 0x7fffu + ((u >> 16) & 1u)) >> 16);
}

// ---------------- K1a: vg_logit in fp64 (+ zero counters) ----------------
__global__ __launch_bounds__(256) void k1_logits(const float* __restrict__ g_feat,
                                                 const float* __restrict__ text,
                                                 double* __restrict__ logits,
                                                 int* __restrict__ cnt,
                                                 int* __restrict__ flagcnt) {
    int b = blockIdx.x;
    int wid = threadIdx.x >> 6, lane = threadIdx.x & 63;
    int t = blockIdx.y * 4 + wid;           // grid.y = 250 -> t in [0,1000)
    if (b == 0 && blockIdx.y == 0) {
        for (int i = threadIdx.x; i < B_ * K_; i += 256) cnt[i] = 0;
        if (threadIdx.x == 0) flagcnt[0] = 0;
    }
    const float* g = g_feat + b * C_;
    const float* e = text + t * C_;
    double s = 0.0;
    #pragma unroll
    for (int j = 0; j < 12; ++j) {
        int c = lane + 64 * j;
        s += (double)g[c] * (double)e[c];
    }
    #pragma unroll
    for (int m = 32; m; m >>= 1) s += __shfl_xor(s, m);
    if (lane == 0) logits[b * T_ + t] = s;
}

// ---------------- K1b: top-20 + gather + A-fragment-ordered bf16 hi/lo pack ----------------
__global__ __launch_bounds__(256) void k1b_topk(const double* __restrict__ logits,
                                                const float* __restrict__ text,
                                                float* __restrict__ agg,
                                                unsigned short* __restrict__ Epk) {
    __shared__ unsigned short hiL[32 * C_];   // 48 KB
    __shared__ unsigned short loL[32 * C_];   // 48 KB
    __shared__ int ssel[K_];
    int b = blockIdx.x, tid = threadIdx.x, lane = tid & 63;
    if (tid < 64) {
        double v[16];
        #pragma unroll
        for (int j = 0; j < 16; ++j) {
            int t = lane + 64 * j;
            v[j] = (t < T_) ? logits[b * T_ + t] : -DBL_MAX;
        }
        for (int it = 0; it < K_; ++it) {
            double bv = -DBL_MAX; int bi = 0x7fffffff;
            #pragma unroll
            for (int j = 0; j < 16; ++j) {
                int t = lane + 64 * j;
                if (v[j] > bv) { bv = v[j]; bi = t; }
            }
            #pragma unroll
            for (int m = 32; m; m >>= 1) {
                double ov = __shfl_xor(bv, m); int oi = __shfl_xor(bi, m);
                if (ov > bv || (ov == bv && oi < bi)) { bv = ov; bi = oi; }
            }
            if (lane == 0) ssel[it] = bi;
            #pragma unroll
            for (int j = 0; j < 16; ++j) {
                int t = lane + 64 * j;
                if (t == bi) v[j] = -DBL_MAX;
            }
        }
    }
    __syncthreads();
    for (int i = tid; i < 32 * C_; i += 256) {
        int r = i / C_, c = i - r * C_;
        float v = (r < K_) ? text[ssel[r] * C_ + c] : 0.f;
        if (r < K_) agg[b * K_ * C_ + i] = v;
        unsigned u = __float_as_uint(v);
        float fh = __uint_as_float(u & 0xffff0000u);
        hiL[i] = (unsigned short)(u >> 16);
        loL[i] = bf_rne(v - fh);
    }
    __syncthreads();
    for (int i = tid; i < 24 * 256; i += 256) {
        int p = i >> 8, r = i & 255, f = r >> 6, ln = r & 63;
        int row = (f & 1) * 16 + (ln & 15);
        int col = p * 32 + (ln >> 4) * 8;
        const unsigned short* src = ((f < 2) ? hiL : loL) + row * C_ + col;
        *(s16x8*)(Epk + ((size_t)b * 6144 + i) * 8) = *(const s16x8*)src;
    }
}

// ---------------- K2: LDS-free MFMA argmax, NT feat reads (best serial: R17) ----------------
__global__ __launch_bounds__(256, 4) void k2_argmax(const float* __restrict__ feat,
                                                    const unsigned short* __restrict__ Epk,
                                                    int* __restrict__ kidx,
                                                    int* __restrict__ cnt,
                                                    int* __restrict__ flagcnt,
                                                    int* __restrict__ flaglist) {
    __shared__ int scnt[K_];
    int tid = threadIdx.x, wid = tid >> 6, lane = tid & 63;
    if (tid < K_) scnt[tid] = 0;
    __syncthreads();

    int gw = blockIdx.x * 4 + wid;           // global wave 0..8191
    int b  = gw >> 8;                        // 256 waves per batch
    int n0 = (gw & 255) * 16;                // pixel base within batch
    int prow = lane & 15;                    // my pixel within the tile
    int g    = lane >> 4;                    // my k-group (0..3)
    const float* fp0 = feat + ((size_t)b * N_ + n0 + prow) * C_ + g * 8;
    const unsigned short* Eb = Epk + (size_t)b * 6144 * 8;

    f32x4 fA[2 * SPP], fB[2 * SPP];
    auto LOADSP = [&](int sp, f32x4* fr) {
        #pragma unroll
        for (int q = 0; q < SPP; ++q) {       // ascending addresses: 512B/row burst
            fr[2 * q]     = __builtin_nontemporal_load((const f32x4*)(fp0 + (sp * SPP + q) * PHC));
            fr[2 * q + 1] = __builtin_nontemporal_load((const f32x4*)(fp0 + (sp * SPP + q) * PHC + 4));
        }
    };

    s16x8 Ah0, Ah1, Al0, Al1;
    auto LOADA = [&](int p) {
        const s16x8* ap = (const s16x8*)(Eb + (size_t)p * 256 * 8);
        Ah0 = ap[lane]; Ah1 = ap[64 + lane];
        Al0 = ap[128 + lane]; Al1 = ap[192 + lane];
    };
    auto CVT = [&](f32x4 a, f32x4 c, s16x8& H, s16x8& L) {
        float x[8] = { a.x, a.y, a.z, a.w, c.x, c.y, c.z, c.w };
        unsigned hu[8], lu[8];
        #pragma unroll
        for (int j = 0; j < 8; ++j) {
            unsigned u = __float_as_uint(x[j]);
            hu[j] = u >> 16;
            lu[j] = bf_rne(x[j] - __uint_as_float(u & 0xffff0000u));
        }
        i32x4 hv = { (int)(hu[0] | (hu[1] << 16)), (int)(hu[2] | (hu[3] << 16)),
                     (int)(hu[4] | (hu[5] << 16)), (int)(hu[6] | (hu[7] << 16)) };
        i32x4 lv = { (int)(lu[0] | (lu[1] << 16)), (int)(lu[2] | (lu[3] << 16)),
                     (int)(lu[4] | (lu[5] << 16)), (int)(lu[6] | (lu[7] << 16)) };
        H = __builtin_bit_cast(s16x8, hv);
        L = __builtin_bit_cast(s16x8, lv);
    };

    f32x4 acc0 = (f32x4)0.f, acc1 = (f32x4)0.f;
    LOADSP(0, fA);

    #pragma unroll 1
    for (int sp = 0; sp < NSP; ++sp) {
        f32x4* cur = (sp & 1) ? fB : fA;
        f32x4* nxt = (sp & 1) ? fA : fB;
        if (sp + 1 < NSP) LOADSP(sp + 1, nxt);   // in flight through 4 phases
        #pragma unroll
        for (int q = 0; q < SPP; ++q) {
            LOADA(sp * SPP + q);                  // 4 L2-hot 1KB wave-loads
            s16x8 Bh, Bl;
            CVT(cur[2 * q], cur[2 * q + 1], Bh, Bl);
            acc0 = __builtin_amdgcn_mfma_f32_16x16x32_bf16(Ah0, Bh, acc0, 0, 0, 0);
            acc1 = __builtin_amdgcn_mfma_f32_16x16x32_bf16(Ah1, Bh, acc1, 0, 0, 0);
            acc0 = __builtin_amdgcn_mfma_f32_16x16x32_bf16(Ah0, Bl, acc0, 0, 0, 0);
            acc1 = __builtin_amdgcn_mfma_f32_16x16x32_bf16(Ah1, Bl, acc1, 0, 0, 0);
            acc0 = __builtin_amdgcn_mfma_f32_16x16x32_bf16(Al0, Bh, acc0, 0, 0, 0);
            acc1 = __builtin_amdgcn_mfma_f32_16x16x32_bf16(Al1, Bh, acc1, 0, 0, 0);
        }
    }

    // epilogue: top-2 over k (C/D: col=lane&15=px, row-class=(lane>>4)*4+reg)
    int kb = g * 4;
    float m1 = acc0[0]; int i1 = kb; float m2 = -FLT_MAX;
    #pragma unroll
    for (int r = 1; r < 4; ++r) {
        float v = acc0[r];
        if (v > m1) { m2 = m1; m1 = v; i1 = kb + r; }
        else if (v > m2) m2 = v;
    }
    if (g == 0) {                            // k-tile 1: only classes 16..19 valid
        #pragma unroll
        for (int r = 0; r < 4; ++r) {
            float v = acc1[r];
            if (v > m1) { m2 = m1; m1 = v; i1 = 16 + r; }
            else if (v > m2) m2 = v;
        }
    }
    #pragma unroll
    for (int s = 16; s < 64; s <<= 1) {
        float om1 = __shfl_xor(m1, s); int oi1 = __shfl_xor(i1, s);
        float om2 = __shfl_xor(m2, s);
        if (om1 > m1 || (om1 == m1 && oi1 < i1)) { m2 = fmaxf(m1, om2); m1 = om1; i1 = oi1; }
        else { m2 = fmaxf(m2, om1); }
    }
    if (lane < 16) {
        int n = n0 + lane;
        kidx[b * N_ + n] = i1;
        atomicAdd(&scnt[i1], 1);
        if (m1 - m2 < GAP_TH) {
            int pos = atomicAdd(flagcnt, 1);
            if (pos < MAXF) flaglist[pos] = b * N_ + n;
        }
    }
    __syncthreads();
    if (tid < K_) atomicAdd(&cnt[b * K_ + tid], scnt[tid]);
}

// ---------------- K2.5: fp64 re-decision for knife-edge pixels ----------------
__global__ __launch_bounds__(256) void k25_refine(const float* __restrict__ feat,
                                                  const float* __restrict__ agg,
                                                  int* __restrict__ kidx,
                                                  int* __restrict__ cnt,
                                                  const int* __restrict__ flagcnt,
                                                  const int* __restrict__ flaglist) {
    int wid = threadIdx.x >> 6, lane = threadIdx.x & 63;
    int wg = blockIdx.x * 4 + wid;
    int nf = flagcnt[0]; if (nf > MAXF) nf = MAXF;
    for (int e = wg; e < nf; e += gridDim.x * 4) {
        int pix = flaglist[e];
        int b = pix >> 12;
        const float* fr = feat + (size_t)pix * C_;
        const float* ebase = agg + b * K_ * C_;
        double fd[12];
        #pragma unroll
        for (int j = 0; j < 12; ++j) fd[j] = (double)fr[lane + 64 * j];
        double best = -DBL_MAX; int bi = 0;
        for (int k = 0; k < K_; ++k) {
            const float* er = ebase + k * C_;
            double s = 0.0;
            #pragma unroll
            for (int j = 0; j < 12; ++j) s += fd[j] * (double)er[lane + 64 * j];
            #pragma unroll
            for (int m = 32; m; m >>= 1) s += __shfl_xor(s, m);
            if (s > best) { best = s; bi = k; }
        }
        if (lane == 0) {
            int old = kidx[pix];
            if (old != bi) {
                kidx[pix] = bi;
                atomicSub(&cnt[b * K_ + old], 1);
                atomicAdd(&cnt[b * K_ + bi], 1);
            }
        }
    }
}

// ---------------- K3s: pre-scale agg rows by 1/(cnt+1) ----------------
__global__ __launch_bounds__(256) void k3s_scale(const float* __restrict__ agg,
                                                 const int* __restrict__ cnt,
                                                 float* __restrict__ sagg) {
    __shared__ float sc[K_];
    int b = blockIdx.x, tid = threadIdx.x;
    if (tid < K_) sc[tid] = 1.0f / ((float)cnt[b * K_ + tid] + 1.0f);  // IEEE div, matches ref
    __syncthreads();
    const f32x4* a4 = (const f32x4*)(agg + (size_t)b * K_ * C_);
    f32x4* s4 = (f32x4*)(sagg + (size_t)b * K_ * C_);
    #pragma unroll 1
    for (int i = tid; i < K_ * (C_ / 4); i += 256) {
        int k = i / (C_ / 4);
        s4[i] = a4[i] * sc[k];
    }
}

// ---------------- K4: gather+store only (8 px/wave, 2-deep pipeline) ----------------
__global__ __launch_bounds__(256) void k4_out(const float* __restrict__ sagg,
                                              const int* __restrict__ kidx,
                                              float* __restrict__ out) {
    int wid = threadIdx.x >> 6, lane = threadIdx.x & 63;
    int wg = blockIdx.x * 4 + wid;          // 16384 waves, 8 px each
    int base = wg * 8;
    int b = base >> 12;                     // wave-uniform (8 | 4096)
    int kk[8];
    #pragma unroll
    for (int i = 0; i < 8; ++i) kk[i] = kidx[base + i];
    const f32x4* sagg4 = (const f32x4*)sagg;
    f32x4* out4 = (f32x4*)out;

    f32x4 va0, va1, va2, vb0, vb1, vb2;
    {
        const f32x4* a4 = sagg4 + (size_t)(b * K_ + kk[0]) * (C_ / 4);
        va0 = a4[lane]; va1 = a4[lane + 64]; va2 = a4[lane + 128];
    }
    #pragma unroll
    for (int i = 0; i < 8; ++i) {
        if (i + 1 < 8) {
            const f32x4* a4 = sagg4 + (size_t)(b * K_ + kk[i + 1]) * (C_ / 4);
            vb0 = a4[lane]; vb1 = a4[lane + 64]; vb2 = a4[lane + 128];
        }
        f32x4* o4 = out4 + (size_t)(base + i) * (C_ / 4);
        o4[lane] = va0; o4[lane + 64] = va1; o4[lane + 128] = va2;
        va0 = vb0; va1 = vb1; va2 = vb2;
    }
}

extern "C" void kernel_launch(void* const* d_in, const int* in_sizes, int n_in,
                              void* d_out, int out_size, void* d_ws, size_t ws_size,
                              hipStream_t stream) {
    const float* g_feat = (const float*)d_in[0];
    const float* feat   = (const float*)d_in[1];
    // d_in[2] = tau: positive scale, numerically irrelevant (attn == y_hard exactly)
    const float* text   = (const float*)d_in[3];
    float* out = (float*)d_out;

    char* ws = (char*)d_ws;
    double* logits        = (double*)(ws + 0);         // 256000 B
    float*  agg           = (float*) (ws + 262144);    // 1966080 B
    int*    cnt           = (int*)   (ws + 2230784);   // 2560 B
    int*    flagc         = (int*)   (ws + 2233344);   // 64 B
    int*    flagl         = (int*)   (ws + 2233408);   // 65536 B
    int*    kidx          = (int*)   (ws + 2301504);   // 524288 B
    unsigned short* Epk   = (unsigned short*)(ws + 2825792);  // 3145728 B
    float*  sagg          = (float*) (ws + 5971520);   // 1966080 B

    k1_logits<<<dim3(32, 250), 256, 0, stream>>>(g_feat, text, logits, cnt, flagc);
    k1b_topk<<<32, 256, 0, stream>>>(logits, text, agg, Epk);
    k2_argmax<<<2048, 256, 0, stream>>>(feat, Epk, kidx, cnt, flagc, flagl);
    k25_refine<<<1024, 256, 0, stream>>>(feat, agg, kidx, cnt, flagc, flagl);
    k3s_scale<<<32, 256, 0, stream>>>(agg, cnt, sagg);
    k4_out<<<4096, 256, 0, stream>>>(sagg, kidx, out);
}